// Round 18
// baseline (237.931 us; speedup 1.0000x reference)
//
#include <hip/hip_runtime.h>

#define NPTS   8192
#define CCH    32
#define LDIM   64
#define ODIM   128
#define KNN    16
#define QPB    64                  // queries per block (16 per wave = MFMA tile rows)
#define TILEC  128                 // candidates per LDS tile
#define NTIL   (NPTS / TILEC)      // 64
#define NBLK   ((4 * NPTS) / QPB)  // 512 blocks
#define SCAP   57                  // survivor capacity (worst ~40); odd stride -> conflict-free rank reads
#define MARGIN 0.75f               // >= 2*eps bound for fp16 distance error
#define T32STR 65                  // t32 row stride (odd -> conflict-free column reads)

typedef _Float16 half8   __attribute__((ext_vector_type(8)));
typedef float    float4v __attribute__((ext_vector_type(4)));

// CHAMPION (R17: 194.3us dispatch / 234.7us bench -- best) + ONE change:
// s_setprio(1) around the consume phase (T5). Mechanism: each CU hosts 4
// independently-phased scan domains (2 blocks x 2 wave-groups, staggered tile
// order), so staging-phase and MFMA/VALU-consume-phase waves coexist; setprio
// biases issue arbitration toward consume waves (attn analog: +4-7%, m191).
// Pure scheduler hint -- scan math byte-identical, absmax must stay 0.
// Sync-policy matrix COMPLETE on this structure: drain-per-tile (R15, 192.4)
// == depth-2 counted-vmcnt (R17, 194.3). Keeping R17's counted form.
//
// LDS map (71424 B -> 2 blocks/CU):
//  scan:   bufs 3/group @ g*26112 + k*8704, 6 x 8704 = 52224 (8192 xh + 512 sq)
//          slist @52224 (14592) | scnt @66816 (256) | tq @67072 (256)
//          kn @67328 (4096) -> total 71424
//          t32 overlay @0 (16640) after pass-1 drain (dead before pass-2 staging)
//  pass3:  skeys overlay @0 (14592)   (stage bufs dead)
//  epilog: pl @0 (8448) | hh @8704 (16640)   (kn alive @67328)
#define LDS_BYTES 71424
#define OFF_SQ   8192              // sq row offset inside a stage buffer
#define OFF_SL   52224
#define OFF_SC   66816
#define OFF_TQ   67072
#define OFF_KN   67328
#define OFF_HH   8704

__device__ __forceinline__ void gload_lds16(const void* g, void* l) {
    __builtin_amdgcn_global_load_lds(
        (const __attribute__((address_space(1))) unsigned int*)g,
        (__attribute__((address_space(3))) unsigned int*)l, 16, 0, 0);
}
__device__ __forceinline__ void gload_lds4(const void* g, void* l) {
    __builtin_amdgcn_global_load_lds(
        (const __attribute__((address_space(1))) unsigned int*)g,
        (__attribute__((address_space(3))) unsigned int*)l, 4, 0, 0);
}

// Prep (R16, verified): one 128-point record per block, 256 blocks; coalesced
// load -> LDS [128][33] -> bit-identical sq -> coalesced fp16 slot writes.
__global__ __launch_bounds__(256)
void prep_kernel(const float* __restrict__ x, float* __restrict__ sqg,
                 _Float16* __restrict__ xh) {
    __shared__ float lx[128 * 33];
    const int r = blockIdx.x;
    const int t = threadIdx.x;
    const float* src = x + (size_t)r * 4096;

    #pragma unroll
    for (int i = 0; i < 4; ++i) {
        int f4 = t + i * 256;
        float4 v = ((const float4*)src)[f4];
        int f = f4 * 4, pt = f >> 5, ch = f & 31;
        float* d = lx + pt * 33 + ch;
        d[0] = v.x; d[1] = v.y; d[2] = v.z; d[3] = v.w;
    }
    __syncthreads();
    if (t < 128) {
        const float* row = lx + t * 33;
        float s = 0.f;
        #pragma unroll
        for (int k = 0; k < 8; ++k) {
            float a = row[4*k], b = row[4*k+1], c = row[4*k+2], d = row[4*k+3];
            s += a * a + b * b + c * c + d * d;
        }
        sqg[r * 128 + t] = s;
    }
    char* rec = (char*)xh + (size_t)r * 8192;
    #pragma unroll
    for (int i = 0; i < 2; ++i) {
        int s2 = t * 2 + i;
        int st = s2 >> 6, q = (s2 >> 4) & 3, col = s2 & 15;
        const float* row = lx + (st * 16 + col) * 33 + q * 8;
        half8 h;
        #pragma unroll
        for (int j = 0; j < 8; ++j) h[j] = (_Float16)row[j];
        *(half8*)(rec + s2 * 16) = h;
    }
}

__global__ __launch_bounds__(512, 4)
void graph_layer_kernel(const float* __restrict__ x,
                        const float* __restrict__ sqg,
                        const _Float16* __restrict__ xh,
                        const float* __restrict__ Wl,
                        const float* __restrict__ bl,
                        const float* __restrict__ Wc,
                        const float* __restrict__ bc,
                        float* __restrict__ out)
{
    __shared__ __align__(16) char smem[LDS_BYTES];
    int*   slist = (int*)(smem + OFF_SL);
    float* t32   = (float*)smem;               // overlay on stage bufs, post-pass-1
    int*   scnt  = (int*)(smem + OFF_SC);
    float* tq    = (float*)(smem + OFF_TQ);
    float* skeys = (float*)smem;               // pass-3 overlay
    int*   kn    = (int*)(smem + OFF_KN);
    float* pl    = (float*)smem;               // epilogue overlays
    float* hh    = (float*)(smem + OFF_HH);

    const int tid  = threadIdx.x;
    const int lane = tid & 63;
    const int w    = tid >> 6;                 // 0..7
    const int g    = w >> 2;                   // wave group: 0 = even tiles, 1 = odd
    const int lw   = w & 3;                    // wave within group
    const int col  = lane & 15;                // candidate column / A-frag row
    const int quad = lane >> 4;
    const float INF = __builtin_inff();

    // XCD-aware swizzle (R15-verified: FETCH 20.4->6.3MB). Bijective on [0,512).
    const int bid = blockIdx.x;
    const int xcd = bid & 7, ixc = bid >> 3;
    const int vb  = ((xcd >> 1) << 7) | ((xcd & 1) << 6) | ixc;

    const int qb0 = vb * QPB;
    const int b   = qb0 >> 13;
    const int qbl = qb0 & (NPTS - 1);
    const int S   = vb & 31;                   // tile-order stagger
    const float* xb  = x   + (size_t)(b << 13) * CCH;
    const float* sqb = sqg + (b << 13);
    const char*  xhb = (const char*)xh + (size_t)b * NTIL * 8192;

    // ---- A-fragment from fp16 workspace: A[m=col][k=quad*8+j], queries lw*16+col
    half8 qh;
    {
        int p = qb0 + lw * 16 + col;
        qh = *(const half8*)((const char*)xh
              + (size_t)(p >> 7) * 8192 + ((p >> 4) & 7) * 1024
              + quad * 256 + (p & 15) * 16);
    }
    asm volatile("s_waitcnt vmcnt(0)" ::: "memory");   // exact vmcnt counts from here

    auto tileof = [&](int I) { return (((I + S) & 31) << 1) | g; };

    // stage: EXACTLY 3 VMEM per wave (2x gload16 frag + 1x gload4 sq, lanes<32)
    auto stage_to = [&](char* sb, int I) {
        int tile = tileof(I);
        const char* src = xhb + (size_t)tile * 8192;
        int tg = tid & 255;                     // thread index within group
        gload_lds16(src + tg * 16,        sb + lw * 1024);   // lds = base + lane*16
        gload_lds16(src + 4096 + tg * 16, sb + 4096 + lw * 1024);
        if (lane < 32)                          // all 4 waves: 32 lanes x 4B = 128B each
            gload_lds4(sqb + tile * TILEC + lw * 32 + lane, sb + OFF_SQ + lw * 128);
    };

    // ================= PASS 1: branch-free per-lane top-2 per query ==========
    float m1[4] = {INF, INF, INF, INF};
    float m2[4] = {INF, INF, INF, INF};

    {
        char* base = smem + g * 26112;
        char *p0 = base, *p1 = base + 8704, *p2 = base + 17408;
        stage_to(p0, 0); stage_to(p1, 1);
        asm volatile("s_waitcnt vmcnt(3)" ::: "memory");   // retire stage(0), keep stage(1)
        __builtin_amdgcn_s_barrier();
        __builtin_amdgcn_sched_barrier(0);
        #pragma unroll 1
        for (int I = 0; I < 32; ++I) {
            stage_to(p2, I + 2);               // wrapped at tail: harmless restage
            __builtin_amdgcn_s_setprio(1);     // T5: favor consume-phase wave
            const float* sv = (const float*)(p0 + OFF_SQ);
            #pragma unroll
            for (int st = 0; st < 8; ++st) {
                half8 bh = *(const half8*)(p0 + st * 1024 + lane * 16);  // conflict-free
                float sc = sv[st * 16 + col];
                float4v acc = __builtin_amdgcn_mfma_f32_16x16x32_f16(
                    qh, bh, (float4v){0.f, 0.f, 0.f, 0.f}, 0, 0, 0);
                #pragma unroll
                for (int j = 0; j < 4; ++j) {
                    float key = fmaf(-2.f, acc[j], sc);
                    float o1  = m1[j];
                    m1[j] = fminf(key, o1);
                    // 2nd-smallest of {key,o1,m2} == min(m2, max(key,o1)) given o1<=m2
                    m2[j] = __builtin_amdgcn_fmed3f(key, o1, m2[j]);
                }
            }
            __builtin_amdgcn_s_setprio(0);
            asm volatile("s_waitcnt vmcnt(3)" ::: "memory");  // retire stage(I+1), keep I+2
            __builtin_amdgcn_s_barrier();
            __builtin_amdgcn_sched_barrier(0);
            char* t_ = p0; p0 = p1; p1 = p2; p2 = t_;
        }
    }
    __syncthreads();   // full drain (wrapped stages in flight) before t32 overlay

    // ---- per-query threshold: 16th smallest of the 64-value union ----
    // Rank-based (exact, lex tie-break): rank(i) = #{j : v_j < v_i or (==, j<i)}.
    #pragma unroll
    for (int j = 0; j < 4; ++j) {
        int qq = lw * 16 + quad * 4 + j;
        t32[qq * T32STR + g * 32 + col * 2 + 0] = m1[j];
        t32[qq * T32STR + g * 32 + col * 2 + 1] = m2[j];
    }
    __syncthreads();
    {
        int q  = tid & 63;                     // query
        int wt = tid >> 6;                     // worker 0..7, items wt*8..wt*8+7
        float v[8]; int r[8];
        #pragma unroll
        for (int u = 0; u < 8; ++u) { v[u] = t32[q * T32STR + wt * 8 + u]; r[u] = 0; }
        #pragma unroll 8
        for (int jj = 0; jj < 64; ++jj) {
            float vj = t32[q * T32STR + jj];   // odd stride -> 2-way max, no conflicts
            #pragma unroll
            for (int u = 0; u < 8; ++u)
                r[u] += (int)(vj < v[u]) | ((int)(vj == v[u]) & (int)(jj < wt * 8 + u));
        }
        #pragma unroll
        for (int u = 0; u < 8; ++u)
            if (r[u] == KNN - 1) tq[q] = v[u];
        if (tid < QPB) scnt[tid] = 0;
    }
    __syncthreads();
    float T2[4];
    #pragma unroll
    for (int j = 0; j < 4; ++j) T2[j] = tq[lw * 16 + quad * 4 + j] + MARGIN;

    // ================= PASS 2: rescan, atomic survivor append ==========
    {
        char* base = smem + g * 26112;
        char *p0 = base, *p1 = base + 8704, *p2 = base + 17408;
        stage_to(p0, 0); stage_to(p1, 1);
        asm volatile("s_waitcnt vmcnt(3)" ::: "memory");
        __builtin_amdgcn_s_barrier();
        __builtin_amdgcn_sched_barrier(0);
        #pragma unroll 1
        for (int I = 0; I < 32; ++I) {
            stage_to(p2, I + 2);
            __builtin_amdgcn_s_setprio(1);
            const float* sv = (const float*)(p0 + OFF_SQ);
            int tbase = tileof(I) * TILEC;
            #pragma unroll
            for (int st = 0; st < 8; ++st) {
                half8 bh = *(const half8*)(p0 + st * 1024 + lane * 16);
                float sc = sv[st * 16 + col];
                float4v acc = __builtin_amdgcn_mfma_f32_16x16x32_f16(
                    qh, bh, (float4v){0.f, 0.f, 0.f, 0.f}, 0, 0, 0);
                #pragma unroll
                for (int j = 0; j < 4; ++j) {
                    float key = fmaf(-2.f, acc[j], sc);
                    if (key < T2[j]) {
                        int qq = lw * 16 + quad * 4 + j;
                        int slot = atomicAdd(&scnt[qq], 1);
                        if (slot < SCAP)
                            slist[qq * SCAP + slot] = tbase + st * 16 + col;
                    }
                }
            }
            __builtin_amdgcn_s_setprio(0);
            asm volatile("s_waitcnt vmcnt(3)" ::: "memory");
            __builtin_amdgcn_s_barrier();
            __builtin_amdgcn_sched_barrier(0);
            char* t_ = p0; p0 = p1; p1 = p2; p2 = t_;
        }
    }
    __syncthreads();   // full drain before skeys overlay

    // ================= PASS 3: exact fp32 re-check of survivors ==========
    {
        int qq = tid & 63, sb8 = tid >> 6;     // 8 workers per query
        int n = scnt[qq]; if (n > SCAP) n = SCAP;
        const float4* xi4 = (const float4*)(xb + (size_t)(qbl + qq) * CCH);
        for (int s = sb8; s < n; s += 8) {
            int jdx = slist[qq * SCAP + s];
            const float4* xj = (const float4*)(xb + (size_t)jdx * CCH);
            float a0 = 0.f, a1 = 0.f, a2 = 0.f, a3 = 0.f;
            #pragma unroll 2
            for (int k = 0; k < 8; ++k) {
                float4 cv = xj[k], qv = xi4[k];
                a0 = fmaf(cv.x, qv.x, a0); a1 = fmaf(cv.y, qv.y, a1);
                a2 = fmaf(cv.z, qv.z, a2); a3 = fmaf(cv.w, qv.w, a3);
            }
            float dot = (a0 + a1) + (a2 + a3);
            skeys[qq * SCAP + s] = fmaf(-2.f, dot, sqb[jdx]);
        }
    }
    __syncthreads();
    // ---- exact top-16 set via rank (lex on (key, idx)); kn order = rank.
    // n >= 16 guaranteed (threshold >= true 16th + MARGIN covers fp16 error).
    {
        int q  = tid & 63;
        int wt = tid >> 6;
        int n = scnt[q]; if (n > SCAP) n = SCAP;
        for (int s = wt; s < n; s += 8) {
            float k = skeys[q * SCAP + s];
            int   i = slist[q * SCAP + s];
            int rank = 0;
            #pragma unroll 4
            for (int jj = 0; jj < n; ++jj) {
                float kj = skeys[q * SCAP + jj];   // stride 57 -> conflict-free
                int   ij = slist[q * SCAP + jj];
                rank += (int)(kj < k) | ((int)(kj == k) & (int)(ij < i));
            }
            if (rank < KNN) kn[q * KNN + rank] = i;
        }
    }
    __syncthreads();

    // ================= epilogue: gather + max-pool + MLP ==========
    {
        int q = tid >> 3, part = tid & 7;      // 8 threads/query, one float4 each
        float4 m0 = make_float4(-INF, -INF, -INF, -INF);
        #pragma unroll 4
        for (int k = 0; k < KNN; ++k) {
            int j = kn[q * KNN + k];
            float4 v = *(const float4*)(xb + (size_t)j * CCH + part * 4);
            m0.x = fmaxf(m0.x, v.x); m0.y = fmaxf(m0.y, v.y);
            m0.z = fmaxf(m0.z, v.z); m0.w = fmaxf(m0.w, v.w);
        }
        float* d = pl + q * 33 + part * 4;
        d[0] = m0.x; d[1] = m0.y; d[2] = m0.z; d[3] = m0.w;
    }
    __syncthreads();
    {
        int l = tid & 63, qg2 = tid >> 6;      // 8 query-slices
        #pragma unroll 1
        for (int qq = qg2; qq < QPB; qq += 8) {
            float acc = bl[l];
            #pragma unroll 8
            for (int c = 0; c < CCH; ++c)
                acc = fmaf(pl[qq * 33 + c], Wl[c * LDIM + l], acc);
            hh[qq * 65 + l] = acc;
        }
    }
    __syncthreads();
    {
        int o = tid & 127, qh2 = tid >> 7;     // 4 query-slices
        #pragma unroll 1
        for (int qq = qh2; qq < QPB; qq += 4) {
            float acc = bc[o];
            #pragma unroll 8
            for (int l = 0; l < LDIM; ++l)
                acc = fmaf(hh[qq * 65 + l], Wc[l * ODIM + o], acc);
            out[(size_t)(qb0 + qq) * ODIM + o] = fmaxf(acc, 0.f);
        }
    }
}

extern "C" void kernel_launch(void* const* d_in, const int* in_sizes, int n_in,
                              void* d_out, int out_size, void* d_ws, size_t ws_size,
                              hipStream_t stream) {
    const float* x  = (const float*)d_in[0];
    const float* Wl = (const float*)d_in[1];
    const float* bl = (const float*)d_in[2];
    const float* Wc = (const float*)d_in[3];
    const float* bc = (const float*)d_in[4];
    float* out = (float*)d_out;
    float*    sqf = (float*)d_ws;                       // 32768 fp32 = 128 KB
    _Float16* xh  = (_Float16*)((char*)d_ws + 131072);  // 32768 x 32 fp16 = 2 MB, frag-order
    (void)in_sizes; (void)n_in; (void)out_size; (void)ws_size;

    hipLaunchKernelGGL(prep_kernel, dim3(256), dim3(256), 0, stream, x, sqf, xh);
    hipLaunchKernelGGL(graph_layer_kernel, dim3(NBLK), dim3(512), 0, stream,
                       x, sqf, xh, Wl, bl, Wc, bc, out);
}